// Round 10
// baseline (92.189 us; speedup 1.0000x reference)
//
#include <hip/hip_runtime.h>

#define NSAMPLE 32
#define RADI 0.1f
#define WPB 4
#define NSEG 16          // build segments per (batch, block)
#define MARGIN 0.0002f   // query block-select margin (>> f32 rounding)

template <int NCELL>
__device__ __forceinline__ int cell_of(float x) {
    int c = (int)(x * (float)NCELL);   // x >= 0: trunc == floor
    c = c < 0 ? 0 : c;
    return c > (NCELL - 1) ? (NCELL - 1) : c;
}

// K1: pack xyz (N,3) AoS -> float4 (x,y,z,0)
__global__ __launch_bounds__(256) void pack_xyz_kernel(
    const float* __restrict__ xyz, float4* __restrict__ xyz4, int N)
{
    const int i = blockIdx.x * blockDim.x + threadIdx.x;
    if (i < N) {
        float4 v;
        v.x = xyz[i * 3 + 0];
        v.y = xyz[i * 3 + 1];
        v.z = xyz[i * 3 + 2];
        v.w = 0.0f;
        xyz4[i] = v;
    }
}

// K2: one wave per (batch, block, segment): count candidates in my segment.
// Block (bx,by,bz) covers cells [b, b+SPAN-1] per axis.
template <int NCELL, int NBLKA, int SPAN>
__global__ __launch_bounds__(64 * WPB) void count_kernel(
    const float4* __restrict__ xyz4, const int* __restrict__ xyz_cnt,
    int* __restrict__ segcnt, int B)
{
    constexpr int NBLK3 = NBLKA * NBLKA * NBLKA;
    const int wave = threadIdx.x >> 6, lane = threadIdx.x & 63;
    const int gw = blockIdx.x * WPB + wave;
    if (gw >= B * NBLK3 * NSEG) return;
    const int seg = gw % NSEG;
    const int blk = (gw / NSEG) % NBLK3;
    const int b   = gw / (NSEG * NBLK3);
    const int bx = blk % NBLKA, by = (blk / NBLKA) % NBLKA, bz = blk / (NBLKA * NBLKA);

    int xstart = 0;
    for (int i = 0; i < b; ++i) xstart += xyz_cnt[i];
    const int nb = xyz_cnt[b];
    const int seglen = (nb + NSEG - 1) / NSEG;
    const int p0 = seg * seglen;
    const int p1 = min(p0 + seglen, nb);

    int cnt = 0;
    for (int base = p0; base < p1; base += 256) {   // 4 loads in flight
        #pragma unroll
        for (int k = 0; k < 4; ++k) {
            const int p = base + k * 64 + lane;
            bool hit = false;
            if (p < p1) {
                const float4 v = xyz4[xstart + p];
                hit = ((unsigned)(cell_of<NCELL>(v.x) - bx) < (unsigned)SPAN) &
                      ((unsigned)(cell_of<NCELL>(v.y) - by) < (unsigned)SPAN) &
                      ((unsigned)(cell_of<NCELL>(v.z) - bz) < (unsigned)SPAN);
            }
            cnt += (int)__popcll(__ballot(hit));
        }
    }
    if (lane == 0) segcnt[gw] = cnt;
}

// K3: same mapping; append my segment's candidates at my prefix offset.
// Segments ordered by offset + in-segment ballot order -> each block list is
// globally index-sorted. Stores float4{x,y,z, bits(global_idx)}.
template <int NCELL, int NBLKA, int SPAN, int CAP>
__global__ __launch_bounds__(64 * WPB) void fill_kernel(
    const float4* __restrict__ xyz4, const int* __restrict__ xyz_cnt,
    const int* __restrict__ segcnt, float4* __restrict__ blk_pts, int B)
{
    constexpr int NBLK3 = NBLKA * NBLKA * NBLKA;
    const int wave = threadIdx.x >> 6, lane = threadIdx.x & 63;
    const int gw = blockIdx.x * WPB + wave;
    if (gw >= B * NBLK3 * NSEG) return;
    const int seg = gw % NSEG;
    const int blk = (gw / NSEG) % NBLK3;
    const int b   = gw / (NSEG * NBLK3);
    const int bx = blk % NBLKA, by = (blk / NBLKA) % NBLKA, bz = blk / (NBLKA * NBLKA);

    int xstart = 0;
    for (int i = 0; i < b; ++i) xstart += xyz_cnt[i];
    const int nb = xyz_cnt[b];
    const int seglen = (nb + NSEG - 1) / NSEG;
    const int p0 = seg * seglen;
    const int p1 = min(p0 + seglen, nb);

    int off = 0;
    const int sbase = (b * NBLK3 + blk) * NSEG;
    for (int s = 0; s < seg; ++s) off += segcnt[sbase + s];

    float4* __restrict__ dst = blk_pts + (size_t)(b * NBLK3 + blk) * CAP;
    const unsigned long long lt = (1ull << lane) - 1ull;

    int cnt = 0;
    for (int base = p0; base < p1; base += 256) {
        #pragma unroll
        for (int k = 0; k < 4; ++k) {
            const int p = base + k * 64 + lane;
            bool hit = false;
            float4 v;
            if (p < p1) {
                v = xyz4[xstart + p];
                hit = ((unsigned)(cell_of<NCELL>(v.x) - bx) < (unsigned)SPAN) &
                      ((unsigned)(cell_of<NCELL>(v.y) - by) < (unsigned)SPAN) &
                      ((unsigned)(cell_of<NCELL>(v.z) - bz) < (unsigned)SPAN);
            }
            const unsigned long long m = __ballot(hit);
            if (hit) {
                const int slot = off + cnt + (int)__popcll(m & lt);
                if (slot < CAP) {
                    v.w = __int_as_float(xstart + p);
                    dst[slot] = v;
                }
            }
            cnt += (int)__popcll(m);
        }
    }
}

// K4: one wave per query. Ordered ballot scan over the query's block list,
// then direct-gather + coalesced float4 store epilogue.
template <int NCELL, int NBLKA, int SPAN, int CAP>
__global__ __launch_bounds__(64 * WPB, 8) void query_kernel(
    const float4* __restrict__ blk_pts,   // (B*NBLK3, CAP)
    const int*    __restrict__ segcnt,    // (B*NBLK3, NSEG)
    const float*  __restrict__ new_xyz,   // (M,3)
    const int*    __restrict__ new_cnt,   // (B,)
    const float*  __restrict__ features,  // (N,C) C=64
    float* __restrict__ out_grouped,      // (M,C,NSAMPLE)
    float* __restrict__ out_cnt,          // (M,)
    int B, int M, int C)
{
    constexpr int NBLK3 = NBLKA * NBLKA * NBLKA;
    const int wave = threadIdx.x >> 6;
    const int lane = threadIdx.x & 63;
    const int q = blockIdx.x * WPB + wave;
    if (q >= M) return;

    __shared__ int s_idx_all[WPB][NSAMPLE];
    int* __restrict__ s_idx = s_idx_all[wave];
    if (lane < NSAMPLE) s_idx[lane] = 0;   // safe gather target for empty slots

    int b = 0, qacc = 0;
    for (int i = 0; i < B; ++i) {
        const int qc = new_cnt[i];
        if (q < qacc + qc) { b = i; break; }
        qacc += qc;
    }

    const float qx = new_xyz[q * 3 + 0];
    const float qy = new_xyz[q * 3 + 1];
    const float qz = new_xyz[q * 3 + 2];

    // block whose SPAN-cell window contains [q-0.1, q+0.1] per axis
    // (coverage window exceeds the cell step; MARGIN >> f32 rounding)
    const int bxq = min(max((int)floorf((qx - RADI - MARGIN) * (float)NCELL), 0), NBLKA - 1);
    const int byq = min(max((int)floorf((qy - RADI - MARGIN) * (float)NCELL), 0), NBLKA - 1);
    const int bzq = min(max((int)floorf((qz - RADI - MARGIN) * (float)NCELL), 0), NBLKA - 1);
    const int blk = bxq + NBLKA * byq + NBLKA * NBLKA * bzq;

    const int sbase = (b * NBLK3 + blk) * NSEG;
    int lcnt = 0;
    #pragma unroll
    for (int s = 0; s < NSEG; ++s) lcnt += segcnt[sbase + s];
    if (lcnt > CAP) lcnt = CAP;

    const float4* __restrict__ lp = blk_pts + (size_t)(b * NBLK3 + blk) * CAP;
    const unsigned long long lt = (1ull << lane) - 1ull;

    int found = 0, base = 0;
    const int nfull = lcnt & ~255;

    auto test_group = [&](const float4& v, bool inb) {
        const float m3 = fmaxf(fmaxf(fabsf(qx - v.x), fabsf(qy - v.y)),
                               fabsf(qz - v.z));
        const bool c = inb & (m3 < RADI);
        const unsigned long long m = __ballot(c);
        if (c) {
            const int slot = found + (int)__popcll(m & lt);
            if (slot < NSAMPLE) s_idx[slot] = __float_as_int(v.w);
        }
        found += (int)__popcll(m);
    };

    if (nfull > 0) {
        float4 A[4], Bb[4];
        #pragma unroll
        for (int k = 0; k < 4; ++k) A[k] = lp[k * 64 + lane];

        while (true) {
            int nxt = base + 256;
            if (nxt < nfull) {
                #pragma unroll
                for (int k = 0; k < 4; ++k) Bb[k] = lp[nxt + k * 64 + lane];
            }
            #pragma unroll
            for (int k = 0; k < 4; ++k) test_group(A[k], true);
            base = nxt;
            if (found >= NSAMPLE || base >= nfull) break;

            nxt = base + 256;
            if (nxt < nfull) {
                #pragma unroll
                for (int k = 0; k < 4; ++k) A[k] = lp[nxt + k * 64 + lane];
            }
            #pragma unroll
            for (int k = 0; k < 4; ++k) test_group(Bb[k], true);
            base = nxt;
            if (found >= NSAMPLE || base >= nfull) break;
        }
    }
    while (found < NSAMPLE && base < lcnt) {   // masked tail
        #pragma unroll
        for (int k = 0; k < 4; ++k) {
            const int p = base + k * 64 + lane;
            const bool inb = (p < lcnt);
            const float4 v = lp[inb ? p : 0];
            test_group(v, inb);
        }
        base += 256;
    }
    if (found > NSAMPLE) found = NSAMPLE;

    // scattered exec-masked ds_writes must land before cross-lane reads
    asm volatile("s_waitcnt lgkmcnt(0)" ::: "memory");
    __builtin_amdgcn_sched_barrier(0);

    // epilogue: lane owns rows s0..s0+3 (s0=4*(lane&7)), channels c=8k+(lane>>3);
    // store t0=(k*64+lane)*4 -> c=t0>>5, s=t0&31 matches (c, s0..s0+3).
    const int s0  = 4 * (lane & 7);
    const int chi = lane >> 3;
    const int r0 = s_idx[s0 + 0];
    const int r1 = s_idx[s0 + 1];
    const int r2 = s_idx[s0 + 2];
    const int r3 = s_idx[s0 + 3];
    const float k0 = (s0 + 0) < found ? 1.0f : 0.0f;
    const float k1 = (s0 + 1) < found ? 1.0f : 0.0f;
    const float k2 = (s0 + 2) < found ? 1.0f : 0.0f;
    const float k3 = (s0 + 3) < found ? 1.0f : 0.0f;

    const float* __restrict__ f0p = features + (size_t)r0 * C;
    const float* __restrict__ f1p = features + (size_t)r1 * C;
    const float* __restrict__ f2p = features + (size_t)r2 * C;
    const float* __restrict__ f3p = features + (size_t)r3 * C;

    float* __restrict__ og = out_grouped + (size_t)q * (C * NSAMPLE);
    #pragma unroll
    for (int k = 0; k < 8; ++k) {
        const int c = 8 * k + chi;
        float4 v;
        v.x = f0p[c] * k0;
        v.y = f1p[c] * k1;
        v.z = f2p[c] * k2;
        v.w = f3p[c] * k3;
        *reinterpret_cast<float4*>(og + (size_t)(k * 64 + lane) * 4) = v;
    }
    if (lane == 0) out_cnt[q] = (float)found;
}

// Fallback (ws too small): one wave per query, direct AoS scan. Slow, correct.
__global__ __launch_bounds__(64 * WPB, 8) void fallback_kernel(
    const float* __restrict__ xyz, const int* __restrict__ xyz_cnt,
    const float* __restrict__ new_xyz, const int* __restrict__ new_cnt,
    const float* __restrict__ features,
    float* __restrict__ out_grouped, float* __restrict__ out_cnt,
    int B, int M, int C)
{
    const int wave = threadIdx.x >> 6, lane = threadIdx.x & 63;
    const int q = blockIdx.x * WPB + wave;
    if (q >= M) return;

    __shared__ int s_idx_all[WPB][NSAMPLE];
    int* __restrict__ s_idx = s_idx_all[wave];
    if (lane < NSAMPLE) s_idx[lane] = 0;

    int b = 0, qacc = 0, xstart = 0;
    for (int i = 0; i < B; ++i) {
        const int qc = new_cnt[i];
        if (q < qacc + qc) { b = i; break; }
        qacc += qc; xstart += xyz_cnt[i];
    }
    const int nb = xyz_cnt[b];
    const float qx = new_xyz[q * 3 + 0], qy = new_xyz[q * 3 + 1], qz = new_xyz[q * 3 + 2];
    const float* __restrict__ xp = xyz + (size_t)xstart * 3;
    const unsigned long long lt = (1ull << lane) - 1ull;

    int found = 0;
    for (int base = 0; base < nb && found < NSAMPLE; base += 64) {
        const int p = base + lane;
        bool c = false;
        if (p < nb) {
            const float dx = qx - xp[p * 3 + 0];
            const float dy = qy - xp[p * 3 + 1];
            const float dz = qz - xp[p * 3 + 2];
            c = (fabsf(dx) < RADI) && (fabsf(dy) < RADI) && (fabsf(dz) < RADI);
        }
        const unsigned long long m = __ballot(c);
        if (c) {
            const int slot = found + (int)__popcll(m & lt);
            if (slot < NSAMPLE) s_idx[slot] = xstart + p;
        }
        found += (int)__popcll(m);
    }
    if (found > NSAMPLE) found = NSAMPLE;

    asm volatile("s_waitcnt lgkmcnt(0)" ::: "memory");
    __builtin_amdgcn_sched_barrier(0);

    const int s0 = 4 * (lane & 7), chi = lane >> 3;
    const int r0 = s_idx[s0 + 0], r1 = s_idx[s0 + 1], r2 = s_idx[s0 + 2], r3 = s_idx[s0 + 3];
    const float k0 = (s0 + 0) < found ? 1.0f : 0.0f;
    const float k1 = (s0 + 1) < found ? 1.0f : 0.0f;
    const float k2 = (s0 + 2) < found ? 1.0f : 0.0f;
    const float k3 = (s0 + 3) < found ? 1.0f : 0.0f;
    const float* f0p = features + (size_t)r0 * C;
    const float* f1p = features + (size_t)r1 * C;
    const float* f2p = features + (size_t)r2 * C;
    const float* f3p = features + (size_t)r3 * C;
    float* __restrict__ og = out_grouped + (size_t)q * (C * NSAMPLE);
    #pragma unroll
    for (int k = 0; k < 8; ++k) {
        const int c = 8 * k + chi;
        float4 v;
        v.x = f0p[c] * k0; v.y = f1p[c] * k1; v.z = f2p[c] * k2; v.w = f3p[c] * k3;
        *reinterpret_cast<float4*>(og + (size_t)(k * 64 + lane) * 4) = v;
    }
    if (lane == 0) out_cnt[q] = (float)found;
}

template <int NCELL, int NBLKA, int SPAN, int CAP>
static void launch_binned(const float* xyz, const int* xyz_cnt,
                          const float* new_xyz, const int* new_cnt,
                          const float* features, float* out_grouped, float* out_cnt,
                          int B, int N, int M, int C, void* d_ws, hipStream_t stream)
{
    constexpr int NBLK3 = NBLKA * NBLKA * NBLKA;
    const size_t pack_bytes = (size_t)N * sizeof(float4);
    float4* xyz4    = (float4*)d_ws;
    float4* blk_pts = (float4*)((char*)d_ws + pack_bytes);
    int*    segcnt  = (int*)((char*)d_ws + pack_bytes + (size_t)B * NBLK3 * CAP * sizeof(float4));

    hipLaunchKernelGGL(pack_xyz_kernel, dim3((N + 255) / 256), dim3(256), 0, stream,
                       xyz, xyz4, N);
    const int nbw = B * NBLK3 * NSEG;
    hipLaunchKernelGGL((count_kernel<NCELL, NBLKA, SPAN>),
                       dim3((nbw + WPB - 1) / WPB), dim3(64 * WPB), 0, stream,
                       xyz4, xyz_cnt, segcnt, B);
    hipLaunchKernelGGL((fill_kernel<NCELL, NBLKA, SPAN, CAP>),
                       dim3((nbw + WPB - 1) / WPB), dim3(64 * WPB), 0, stream,
                       xyz4, xyz_cnt, segcnt, blk_pts, B);
    hipLaunchKernelGGL((query_kernel<NCELL, NBLKA, SPAN, CAP>),
                       dim3((M + WPB - 1) / WPB), dim3(64 * WPB), 0, stream,
                       blk_pts, segcnt, new_xyz, new_cnt, features,
                       out_grouped, out_cnt, B, M, C);
}

extern "C" void kernel_launch(void* const* d_in, const int* in_sizes, int n_in,
                              void* d_out, int out_size, void* d_ws, size_t ws_size,
                              hipStream_t stream) {
    const float* xyz      = (const float*)d_in[0];
    const int*   xyz_cnt  = (const int*)d_in[1];
    const float* new_xyz  = (const float*)d_in[2];
    const int*   new_cnt  = (const int*)d_in[3];
    const float* features = (const float*)d_in[4];

    const int B = in_sizes[1];
    const int N = in_sizes[0] / 3;
    const int M = in_sizes[2] / 3;
    const int C = in_sizes[4] / N;   // 64

    float* out_grouped = (float*)d_out;
    float* out_cnt     = (float*)d_out + (size_t)M * C * NSAMPLE;

    const size_t pack_bytes = (size_t)N * sizeof(float4);
    // fine: 0.125 cells, 3-cell blocks (0.375 wide), 6^3 = 216 blocks/batch
    const size_t fine_need = pack_bytes
        + (size_t)B * 216 * 1280 * sizeof(float4)
        + (size_t)B * 216 * NSEG * sizeof(int);
    // coarse (R8-proven): 0.25 cells, 2-cell blocks (0.5 wide), 3^3 = 27
    const size_t coarse_need = pack_bytes
        + (size_t)B * 27 * 3072 * sizeof(float4)
        + (size_t)B * 27 * NSEG * sizeof(int);

    if (ws_size >= fine_need) {
        launch_binned<8, 6, 3, 1280>(xyz, xyz_cnt, new_xyz, new_cnt, features,
                                     out_grouped, out_cnt, B, N, M, C, d_ws, stream);
    } else if (ws_size >= coarse_need) {
        launch_binned<4, 3, 2, 3072>(xyz, xyz_cnt, new_xyz, new_cnt, features,
                                     out_grouped, out_cnt, B, N, M, C, d_ws, stream);
    } else {
        hipLaunchKernelGGL(fallback_kernel, dim3((M + WPB - 1) / WPB), dim3(64 * WPB), 0, stream,
                           xyz, xyz_cnt, new_xyz, new_cnt, features,
                           out_grouped, out_cnt, B, M, C);
    }
}

// Round 12
// 74.038 us; speedup vs baseline: 1.2451x; 1.2451x over previous
//
#include <hip/hip_runtime.h>

#define NSAMPLE 32
#define RADI 0.1f
#define WPB 4
#define MARGIN 0.0002f   // query block-select margin (>> f32 rounding)

// coarse binning (R8-proven): 0.25-wide cells, 2-cell blocks (0.5 wide)
#define NCELL 4
#define NBLKA 3
#define SPAN  2
#define NBLK3 27
#define CAP   3072       // per-block capacity (mean 2048, sigma ~42)
#define NSEG  64         // seglen = 256 -> single-chunk build waves

typedef float nat_f32x4 __attribute__((ext_vector_type(4)));  // for nontemporal builtin

__device__ __forceinline__ int cell_of(float x) {
    int c = (int)(x * (float)NCELL);   // x >= 0: trunc == floor
    c = c < 0 ? 0 : c;
    return c > (NCELL - 1) ? (NCELL - 1) : c;
}

// K1: pack xyz (N,3) AoS -> float4 (x,y,z,0)
__global__ __launch_bounds__(256) void pack_xyz_kernel(
    const float* __restrict__ xyz, float4* __restrict__ xyz4, int N)
{
    const int i = blockIdx.x * blockDim.x + threadIdx.x;
    if (i < N) {
        float4 v;
        v.x = xyz[i * 3 + 0];
        v.y = xyz[i * 3 + 1];
        v.z = xyz[i * 3 + 2];
        v.w = 0.0f;
        xyz4[i] = v;
    }
}

// K2: one wave per (batch, block, segment): count candidates in my segment.
// NSEG=64 -> seglen 256 -> exactly one 4x64 chunk per wave (no serial loop).
__global__ __launch_bounds__(64 * WPB) void count_kernel(
    const float4* __restrict__ xyz4, const int* __restrict__ xyz_cnt,
    int* __restrict__ segcnt, int B)
{
    const int wave = threadIdx.x >> 6, lane = threadIdx.x & 63;
    const int gw = blockIdx.x * WPB + wave;
    if (gw >= B * NBLK3 * NSEG) return;
    const int seg = gw % NSEG;
    const int blk = (gw / NSEG) % NBLK3;
    const int b   = gw / (NSEG * NBLK3);
    const int bx = blk % NBLKA, by = (blk / NBLKA) % NBLKA, bz = blk / (NBLKA * NBLKA);

    int xstart = 0;
    for (int i = 0; i < b; ++i) xstart += xyz_cnt[i];
    const int nb = xyz_cnt[b];
    const int seglen = (nb + NSEG - 1) / NSEG;
    const int p0 = seg * seglen;
    const int p1 = min(p0 + seglen, nb);

    int cnt = 0;
    for (int base = p0; base < p1; base += 256) {
        #pragma unroll
        for (int k = 0; k < 4; ++k) {
            const int p = base + k * 64 + lane;
            bool hit = false;
            if (p < p1) {
                const float4 v = xyz4[xstart + p];
                hit = ((unsigned)(cell_of(v.x) - bx) < (unsigned)SPAN) &
                      ((unsigned)(cell_of(v.y) - by) < (unsigned)SPAN) &
                      ((unsigned)(cell_of(v.z) - bz) < (unsigned)SPAN);
            }
            cnt += (int)__popcll(__ballot(hit));
        }
    }
    if (lane == 0) segcnt[gw] = cnt;
}

// K3: same mapping; append my segment's candidates at my prefix offset.
// Segment order + in-segment ballot order -> block lists globally
// index-sorted. Last segment's wave also writes the block total (blkcnt).
__global__ __launch_bounds__(64 * WPB) void fill_kernel(
    const float4* __restrict__ xyz4, const int* __restrict__ xyz_cnt,
    const int* __restrict__ segcnt, float4* __restrict__ blk_pts,
    int* __restrict__ blkcnt, int B)
{
    const int wave = threadIdx.x >> 6, lane = threadIdx.x & 63;
    const int gw = blockIdx.x * WPB + wave;
    if (gw >= B * NBLK3 * NSEG) return;
    const int seg = gw % NSEG;
    const int blk = (gw / NSEG) % NBLK3;
    const int b   = gw / (NSEG * NBLK3);
    const int bx = blk % NBLKA, by = (blk / NBLKA) % NBLKA, bz = blk / (NBLKA * NBLKA);

    int xstart = 0;
    for (int i = 0; i < b; ++i) xstart += xyz_cnt[i];
    const int nb = xyz_cnt[b];
    const int seglen = (nb + NSEG - 1) / NSEG;
    const int p0 = seg * seglen;
    const int p1 = min(p0 + seglen, nb);

    const int bid = b * NBLK3 + blk;
    int off = 0;
    const int sbase = bid * NSEG;
    for (int s = 0; s < seg; ++s) off += segcnt[sbase + s];

    float4* __restrict__ dst = blk_pts + (size_t)bid * CAP;
    const unsigned long long lt = (1ull << lane) - 1ull;

    int cnt = 0;
    for (int base = p0; base < p1; base += 256) {
        #pragma unroll
        for (int k = 0; k < 4; ++k) {
            const int p = base + k * 64 + lane;
            bool hit = false;
            float4 v;
            if (p < p1) {
                v = xyz4[xstart + p];
                hit = ((unsigned)(cell_of(v.x) - bx) < (unsigned)SPAN) &
                      ((unsigned)(cell_of(v.y) - by) < (unsigned)SPAN) &
                      ((unsigned)(cell_of(v.z) - bz) < (unsigned)SPAN);
            }
            const unsigned long long m = __ballot(hit);
            if (hit) {
                const int slot = off + cnt + (int)__popcll(m & lt);
                if (slot < CAP) {
                    v.w = __int_as_float(xstart + p);
                    dst[slot] = v;
                }
            }
            cnt += (int)__popcll(m);
        }
    }
    if (seg == NSEG - 1 && lane == 0) blkcnt[bid] = off + cnt;  // block total
}

// K4: one wave per query. Ordered ballot scan over the query's block list
// (A/B double buffer, wave-uniform mid-chunk early exit), then direct
// gather + coalesced NON-TEMPORAL float4 stores (write-once stream; keep
// L2 for blk_pts/features).
__global__ __launch_bounds__(64 * WPB, 8) void query_kernel(
    const float4* __restrict__ blk_pts,   // (B*NBLK3, CAP)
    const int*    __restrict__ blkcnt,    // (B*NBLK3,)
    const float*  __restrict__ new_xyz,   // (M,3)
    const int*    __restrict__ new_cnt,   // (B,)
    const float*  __restrict__ features,  // (N,C) C=64
    float* __restrict__ out_grouped,      // (M,C,NSAMPLE)
    float* __restrict__ out_cnt,          // (M,)
    int B, int M, int C)
{
    const int wave = threadIdx.x >> 6;
    const int lane = threadIdx.x & 63;
    const int q = blockIdx.x * WPB + wave;
    if (q >= M) return;

    __shared__ int s_idx_all[WPB][NSAMPLE];
    int* __restrict__ s_idx = s_idx_all[wave];
    if (lane < NSAMPLE) s_idx[lane] = 0;   // safe gather target for empty slots

    int b = 0, qacc = 0;
    for (int i = 0; i < B; ++i) {
        const int qc = new_cnt[i];
        if (q < qacc + qc) { b = i; break; }
        qacc += qc;
    }

    const float qx = new_xyz[q * 3 + 0];
    const float qy = new_xyz[q * 3 + 1];
    const float qz = new_xyz[q * 3 + 2];

    // block whose SPAN-cell window contains [q-0.1, q+0.1] per axis
    const int bxq = min(max((int)floorf((qx - RADI - MARGIN) * (float)NCELL), 0), NBLKA - 1);
    const int byq = min(max((int)floorf((qy - RADI - MARGIN) * (float)NCELL), 0), NBLKA - 1);
    const int bzq = min(max((int)floorf((qz - RADI - MARGIN) * (float)NCELL), 0), NBLKA - 1);
    const int bid = b * NBLK3 + bxq + NBLKA * byq + NBLKA * NBLKA * bzq;

    int lcnt = blkcnt[bid];
    if (lcnt > CAP) lcnt = CAP;

    const float4* __restrict__ lp = blk_pts + (size_t)bid * CAP;
    const unsigned long long lt = (1ull << lane) - 1ull;

    int found = 0, base = 0;
    const int nfull = lcnt & ~255;

    auto test_group = [&](const float4& v, bool inb) {
        const float m3 = fmaxf(fmaxf(fabsf(qx - v.x), fabsf(qy - v.y)),
                               fabsf(qz - v.z));
        const bool c = inb & (m3 < RADI);
        const unsigned long long m = __ballot(c);
        if (c) {
            const int slot = found + (int)__popcll(m & lt);
            if (slot < NSAMPLE) s_idx[slot] = __float_as_int(v.w);
        }
        found += (int)__popcll(m);
    };

    if (nfull > 0) {
        float4 A[4], Bb[4];
        #pragma unroll
        for (int k = 0; k < 4; ++k) A[k] = lp[k * 64 + lane];

        while (true) {
            int nxt = base + 256;
            if (nxt < nfull) {
                #pragma unroll
                for (int k = 0; k < 4; ++k) Bb[k] = lp[nxt + k * 64 + lane];
            }
            #pragma unroll
            for (int k = 0; k < 4; ++k) {
                test_group(A[k], true);
                if (found >= NSAMPLE) break;   // wave-uniform (found from ballot)
            }
            base = nxt;
            if (found >= NSAMPLE || base >= nfull) break;

            nxt = base + 256;
            if (nxt < nfull) {
                #pragma unroll
                for (int k = 0; k < 4; ++k) A[k] = lp[nxt + k * 64 + lane];
            }
            #pragma unroll
            for (int k = 0; k < 4; ++k) {
                test_group(Bb[k], true);
                if (found >= NSAMPLE) break;
            }
            base = nxt;
            if (found >= NSAMPLE || base >= nfull) break;
        }
    }
    while (found < NSAMPLE && base < lcnt) {   // masked tail
        #pragma unroll
        for (int k = 0; k < 4; ++k) {
            const int p = base + k * 64 + lane;
            const bool inb = (p < lcnt);
            const float4 v = lp[inb ? p : 0];
            test_group(v, inb);
        }
        base += 256;
    }
    if (found > NSAMPLE) found = NSAMPLE;

    // scattered exec-masked ds_writes must land before cross-lane reads
    asm volatile("s_waitcnt lgkmcnt(0)" ::: "memory");
    __builtin_amdgcn_sched_barrier(0);

    // epilogue: lane owns rows s0..s0+3 (s0=4*(lane&7)), channels c=8k+(lane>>3);
    // store t0=(k*64+lane)*4 -> c=t0>>5, s=t0&31 matches (c, s0..s0+3).
    const int s0  = 4 * (lane & 7);
    const int chi = lane >> 3;
    const int r0 = s_idx[s0 + 0];
    const int r1 = s_idx[s0 + 1];
    const int r2 = s_idx[s0 + 2];
    const int r3 = s_idx[s0 + 3];
    const float k0 = (s0 + 0) < found ? 1.0f : 0.0f;
    const float k1 = (s0 + 1) < found ? 1.0f : 0.0f;
    const float k2 = (s0 + 2) < found ? 1.0f : 0.0f;
    const float k3 = (s0 + 3) < found ? 1.0f : 0.0f;

    const float* __restrict__ f0p = features + (size_t)r0 * C;
    const float* __restrict__ f1p = features + (size_t)r1 * C;
    const float* __restrict__ f2p = features + (size_t)r2 * C;
    const float* __restrict__ f3p = features + (size_t)r3 * C;

    float* __restrict__ og = out_grouped + (size_t)q * (C * NSAMPLE);
    #pragma unroll
    for (int k = 0; k < 8; ++k) {
        const int c = 8 * k + chi;
        nat_f32x4 v;
        v.x = f0p[c] * k0;
        v.y = f1p[c] * k1;
        v.z = f2p[c] * k2;
        v.w = f3p[c] * k3;
        __builtin_nontemporal_store(v,
            reinterpret_cast<nat_f32x4*>(og + (size_t)(k * 64 + lane) * 4));
    }
    if (lane == 0) out_cnt[q] = (float)found;
}

// Fallback (ws too small): one wave per query, direct AoS scan. Slow, correct.
__global__ __launch_bounds__(64 * WPB, 8) void fallback_kernel(
    const float* __restrict__ xyz, const int* __restrict__ xyz_cnt,
    const float* __restrict__ new_xyz, const int* __restrict__ new_cnt,
    const float* __restrict__ features,
    float* __restrict__ out_grouped, float* __restrict__ out_cnt,
    int B, int M, int C)
{
    const int wave = threadIdx.x >> 6, lane = threadIdx.x & 63;
    const int q = blockIdx.x * WPB + wave;
    if (q >= M) return;

    __shared__ int s_idx_all[WPB][NSAMPLE];
    int* __restrict__ s_idx = s_idx_all[wave];
    if (lane < NSAMPLE) s_idx[lane] = 0;

    int b = 0, qacc = 0, xstart = 0;
    for (int i = 0; i < B; ++i) {
        const int qc = new_cnt[i];
        if (q < qacc + qc) { b = i; break; }
        qacc += qc; xstart += xyz_cnt[i];
    }
    const int nb = xyz_cnt[b];
    const float qx = new_xyz[q * 3 + 0], qy = new_xyz[q * 3 + 1], qz = new_xyz[q * 3 + 2];
    const float* __restrict__ xp = xyz + (size_t)xstart * 3;
    const unsigned long long lt = (1ull << lane) - 1ull;

    int found = 0;
    for (int base = 0; base < nb && found < NSAMPLE; base += 64) {
        const int p = base + lane;
        bool c = false;
        if (p < nb) {
            const float dx = qx - xp[p * 3 + 0];
            const float dy = qy - xp[p * 3 + 1];
            const float dz = qz - xp[p * 3 + 2];
            c = (fabsf(dx) < RADI) && (fabsf(dy) < RADI) && (fabsf(dz) < RADI);
        }
        const unsigned long long m = __ballot(c);
        if (c) {
            const int slot = found + (int)__popcll(m & lt);
            if (slot < NSAMPLE) s_idx[slot] = xstart + p;
        }
        found += (int)__popcll(m);
    }
    if (found > NSAMPLE) found = NSAMPLE;

    asm volatile("s_waitcnt lgkmcnt(0)" ::: "memory");
    __builtin_amdgcn_sched_barrier(0);

    const int s0 = 4 * (lane & 7), chi = lane >> 3;
    const int r0 = s_idx[s0 + 0], r1 = s_idx[s0 + 1], r2 = s_idx[s0 + 2], r3 = s_idx[s0 + 3];
    const float k0 = (s0 + 0) < found ? 1.0f : 0.0f;
    const float k1 = (s0 + 1) < found ? 1.0f : 0.0f;
    const float k2 = (s0 + 2) < found ? 1.0f : 0.0f;
    const float k3 = (s0 + 3) < found ? 1.0f : 0.0f;
    const float* f0p = features + (size_t)r0 * C;
    const float* f1p = features + (size_t)r1 * C;
    const float* f2p = features + (size_t)r2 * C;
    const float* f3p = features + (size_t)r3 * C;
    float* __restrict__ og = out_grouped + (size_t)q * (C * NSAMPLE);
    #pragma unroll
    for (int k = 0; k < 8; ++k) {
        const int c = 8 * k + chi;
        float4 v;
        v.x = f0p[c] * k0; v.y = f1p[c] * k1; v.z = f2p[c] * k2; v.w = f3p[c] * k3;
        *reinterpret_cast<float4*>(og + (size_t)(k * 64 + lane) * 4) = v;
    }
    if (lane == 0) out_cnt[q] = (float)found;
}

extern "C" void kernel_launch(void* const* d_in, const int* in_sizes, int n_in,
                              void* d_out, int out_size, void* d_ws, size_t ws_size,
                              hipStream_t stream) {
    const float* xyz      = (const float*)d_in[0];
    const int*   xyz_cnt  = (const int*)d_in[1];
    const float* new_xyz  = (const float*)d_in[2];
    const int*   new_cnt  = (const int*)d_in[3];
    const float* features = (const float*)d_in[4];

    const int B = in_sizes[1];
    const int N = in_sizes[0] / 3;
    const int M = in_sizes[2] / 3;
    const int C = in_sizes[4] / N;   // 64

    float* out_grouped = (float*)d_out;
    float* out_cnt     = (float*)d_out + (size_t)M * C * NSAMPLE;

    const size_t pack_bytes = (size_t)N * sizeof(float4);
    const size_t blk_bytes  = (size_t)B * NBLK3 * CAP * sizeof(float4);
    const size_t seg_bytes  = (size_t)B * NBLK3 * NSEG * sizeof(int);
    const size_t bcn_bytes  = (size_t)B * NBLK3 * sizeof(int);
    const size_t need = pack_bytes + blk_bytes + seg_bytes + bcn_bytes;

    if (ws_size >= need) {
        float4* xyz4    = (float4*)d_ws;
        float4* blk_pts = (float4*)((char*)d_ws + pack_bytes);
        int*    segcnt  = (int*)((char*)d_ws + pack_bytes + blk_bytes);
        int*    blkcnt  = (int*)((char*)d_ws + pack_bytes + blk_bytes + seg_bytes);

        hipLaunchKernelGGL(pack_xyz_kernel, dim3((N + 255) / 256), dim3(256), 0, stream,
                           xyz, xyz4, N);
        const int nbw = B * NBLK3 * NSEG;
        hipLaunchKernelGGL(count_kernel, dim3((nbw + WPB - 1) / WPB), dim3(64 * WPB), 0, stream,
                           xyz4, xyz_cnt, segcnt, B);
        hipLaunchKernelGGL(fill_kernel, dim3((nbw + WPB - 1) / WPB), dim3(64 * WPB), 0, stream,
                           xyz4, xyz_cnt, segcnt, blk_pts, blkcnt, B);
        hipLaunchKernelGGL(query_kernel, dim3((M + WPB - 1) / WPB), dim3(64 * WPB), 0, stream,
                           blk_pts, blkcnt, new_xyz, new_cnt, features,
                           out_grouped, out_cnt, B, M, C);
    } else {
        hipLaunchKernelGGL(fallback_kernel, dim3((M + WPB - 1) / WPB), dim3(64 * WPB), 0, stream,
                           xyz, xyz_cnt, new_xyz, new_cnt, features,
                           out_grouped, out_cnt, B, M, C);
    }
}